// Round 7
// baseline (607.385 us; speedup 1.0000x reference)
//
#include <hip/hip_runtime.h>

#define DM 128
#define NH 8
#define DFF 512

typedef __attribute__((ext_vector_type(8))) short bf16x8;
typedef __attribute__((ext_vector_type(4))) float f32x4;
typedef __attribute__((ext_vector_type(2))) unsigned uintx2;

#define WAITVM(N) do { asm volatile("s_waitcnt vmcnt(" #N ")" ::: "memory"); \
                       __builtin_amdgcn_sched_barrier(0); } while (0)
#define WAITLGKM0 do { asm volatile("s_waitcnt lgkmcnt(0)" ::: "memory"); \
                       __builtin_amdgcn_sched_barrier(0); } while (0)

__device__ __forceinline__ short f2bf(float f) {
    union { float f; unsigned u; } v; v.f = f;
    unsigned r = v.u + 0x7fffu + ((v.u >> 16) & 1u);   // RNE
    return (short)(r >> 16);
}
__device__ __forceinline__ float bf2f(unsigned short b) {
    union { unsigned u; float f; } v; v.u = ((unsigned)b) << 16; return v.f;
}

// ---------------------------------------------------------------------------
// Async-stage a [ROWS x 128] bf16 tile into LDS via global_load_lds (16B/lane).
// LDS linear [row][128 shorts]; 16B chunk index XOR-swizzled on the GLOBAL
// side: LDS (row, kc) holds global (row, kc^(row&15)). Readers use same XOR.
// Ops per thread = ROWS*16/NT.
// ---------------------------------------------------------------------------
template<int ROWS, int NT>
__device__ __forceinline__ void stage_tile(
    const short* __restrict__ g, int row0, int maxrow, int rstride, int kbase,
    short* s, int tid)
{
    const int lane = tid & 63;
#pragma unroll
    for (int rr = 0; rr < ROWS * 16 / NT; ++rr) {
        int idx = rr * NT + tid;                    // 16B-chunk index in tile
        int row = idx >> 4, kc = idx & 15;
        int rg = row0 + row;
        rg = (rg < maxrow) ? rg : (maxrow - 1);
        const short* src = g + (size_t)rg * rstride + kbase
                         + ((kc ^ (row & 15)) << 3);
        short* dst = s + (size_t)(idx - lane) * 8;  // wave-uniform base
        __builtin_amdgcn_global_load_lds(
            (const __attribute__((address_space(1))) void*)src,
            (__attribute__((address_space(3))) void*)dst, 16, 0, 0);
    }
}

// MFMA fragment read from a swizzled [*][128] tile (row stride 128 shorts).
__device__ __forceinline__ bf16x8 frag_ld(const short* s, int row, int ks, int g)
{
    return *(const bf16x8*)(s + row * 128 + ((((ks << 2) + g) ^ (row & 15)) << 3));
}

// ---------------------------------------------------------------------------
// Weight-stationary streaming GEMM, K=128 (layer-0 z projection):
//   out[t*64.., 0..127] = A[64,128] @ Bt[128,128]^T
// 512 thr = 8 waves as 2 row x 4 col (32x32 wave tiles).
// ---------------------------------------------------------------------------
template<bool PRELU, int NOUT>
__global__ __launch_bounds__(512, 4) void gemm_k128_stream(
    const short* __restrict__ A, const short* __restrict__ Bt,
    const float* __restrict__ bias, const float* __restrict__ affp,
    int M, short* __restrict__ outbf)
{
    __shared__ __align__(16) short sW[128 * 128];      // 32 KB
    __shared__ __align__(16) short sA[3][64 * 128];    // 3 x 16 KB

    const int tid = threadIdx.x;
    const int wave = tid >> 6, lane = tid & 63;
    const int wm = wave >> 2, wn = wave & 3;
    const int bn = blockIdx.x * 128;
    const int fr = lane & 15, g = lane >> 4;
    const int lr4 = g << 2;
    const int nT = (M + 63) >> 6;
    const int GY = gridDim.y;
    const int t0 = blockIdx.y;
    const int nLoc = (t0 < nT) ? ((nT - 1 - t0) / GY + 1) : 0;

    float bb[2]; float aff = 0.0f;
    if constexpr (PRELU) {
        aff = *affp;
#pragma unroll
        for (int cg = 0; cg < 2; ++cg)
            bb[cg] = bias[bn + wn * 32 + cg * 16 + fr];
    }

    stage_tile<128, 512>(Bt + (size_t)bn * 128, 0, 128, 128, 0, sW, tid);
    if (nLoc > 0) stage_tile<64, 512>(A, t0 * 64, M, 128, 0, sA[0], tid);
    if (nLoc > 1) stage_tile<64, 512>(A, (t0 + GY) * 64, M, 128, 0, sA[1], tid);

    for (int i = 0; i < nLoc; ++i) {
        const int t = t0 + i * GY;
        if (i >= 1 && i + 1 < nLoc)
            stage_tile<64, 512>(A, (t + GY) * 64, M, 128, 0, sA[(i + 1) % 3], tid);

        if (i == 0) { if (nLoc > 1) { WAITVM(2); } else { WAITVM(0); } }
        else if (i + 1 < nLoc) { WAITVM(18); }
        else { WAITVM(16); }
        __builtin_amdgcn_s_barrier();

        const short* sAb = sA[i % 3];
        f32x4 acc[2][2];
#pragma unroll
        for (int ii = 0; ii < 2; ++ii)
#pragma unroll
            for (int cg = 0; cg < 2; ++cg) acc[ii][cg] = (f32x4)0.0f;

#pragma unroll
        for (int ks = 0; ks < 4; ++ks) {
            bf16x8 af[2], bf[2];
#pragma unroll
            for (int ii = 0; ii < 2; ++ii)
                af[ii] = frag_ld(sAb, wm * 32 + ii * 16 + fr, ks, g);
#pragma unroll
            for (int cg = 0; cg < 2; ++cg)
                bf[cg] = frag_ld(sW, wn * 32 + cg * 16 + fr, ks, g);
#pragma unroll
            for (int ii = 0; ii < 2; ++ii)
#pragma unroll
                for (int cg = 0; cg < 2; ++cg)
                    acc[ii][cg] = __builtin_amdgcn_mfma_f32_16x16x32_bf16(
                        af[ii], bf[cg], acc[ii][cg], 0, 0, 0);
        }

#pragma unroll
        for (int ii = 0; ii < 2; ++ii)
#pragma unroll
            for (int cg = 0; cg < 2; ++cg) {
                int colL = wn * 32 + cg * 16 + fr;
#pragma unroll
                for (int r = 0; r < 4; ++r) {
                    int row = t * 64 + wm * 32 + ii * 16 + lr4 + r;
                    if (row < M) {
                        float v = acc[ii][cg][r];
                        if constexpr (PRELU) {
                            v += bb[cg];
                            v = (v >= 0.0f) ? v : aff * v;
                        }
                        outbf[(size_t)row * NOUT + bn + colL] = f2bf(v);
                    }
                }
            }
    }
}

// ---------------------------------------------------------------------------
// Fully fused FFN + next-layer z projection, chunk-interleaved (no H1 tile):
//   for c in 0..3: H1c = prelu(hn @ W1t[c] + b1[c]) -> sH (16 KB);
//                  acc2 += H1c @ W2t[:,c]
//   x = acc2 + b2 + h -> xo (fp32);  z_next = bf16(x) @ Wnt^T
// Weight stream = 9 chunks through a 2x32KB ping-pong, counted vmcnt(4).
// ALL streaming io (hn, h, xo, z_next) is NON-TEMPORAL so the reused weight
// chunks stay L2-resident (R6 showed streaming io evicted them: 245 MB HBM).
// LDS 80 KB -> 2 blocks/CU, 512 thr (2x4 waves, 32x32 tiles).
// ---------------------------------------------------------------------------
__global__ __launch_bounds__(512, 4) void ffn12z(
    const short* __restrict__ hn, const short* __restrict__ W1t,
    const short* __restrict__ W2t, const short* __restrict__ h_bf,
    const float* __restrict__ b1, const float* __restrict__ b2,
    const float* __restrict__ affp, const short* __restrict__ Wnt,
    int has_next, int M, float* __restrict__ xo, short* __restrict__ z_next)
{
    __shared__ __align__(16) short sW[2][128 * 128];   // 2 x 32 KB weights
    __shared__ __align__(16) short sH[64 * 128];       // 16 KB H1-chunk / x

    const int tid = threadIdx.x;
    const int wave = tid >> 6, lane = tid & 63;
    const int wm = wave >> 2, wn = wave & 3;
    const int bm = blockIdx.x * 64;
    const int fr = lane & 15, g = lane >> 4;
    const int lr4 = g << 2, fk8 = g << 3;

    // ---- prologue: ALL global loads issued here (streams non-temporal) ----
    bf16x8 ah[2][4];
#pragma unroll
    for (int ii = 0; ii < 2; ++ii) {
        int row = bm + wm * 32 + ii * 16 + fr;
        row = (row < M) ? row : (M - 1);
#pragma unroll
        for (int ks = 0; ks < 4; ++ks)
            ah[ii][ks] = __builtin_nontemporal_load(
                (const bf16x8*)(hn + (size_t)row * DM + ks * 32 + fk8));
    }
    unsigned short hres[2][2][4];
    float bb2[2];
#pragma unroll
    for (int ii = 0; ii < 2; ++ii)
#pragma unroll
        for (int cg = 0; cg < 2; ++cg) {
            int colL = wn * 32 + cg * 16 + fr;
            if (ii == 0) bb2[cg] = b2[colL];
#pragma unroll
            for (int r = 0; r < 4; ++r) {
                int row = bm + wm * 32 + ii * 16 + lr4 + r;
                int rc = (row < M) ? row : (M - 1);
                hres[ii][cg][r] = (unsigned short)__builtin_nontemporal_load(
                    h_bf + (size_t)rc * DM + colL);
            }
        }
    float bb1[4][2];
#pragma unroll
    for (int c = 0; c < 4; ++c)
#pragma unroll
        for (int cg = 0; cg < 2; ++cg)
            bb1[c][cg] = b1[c * 128 + wn * 32 + cg * 16 + fr];
    float aff = *affp;

    stage_tile<128, 512>(W1t, 0, 512, 128, 0, sW[0], tid);   // chunk 0

    f32x4 acc2[2][2];
#pragma unroll
    for (int ii = 0; ii < 2; ++ii)
#pragma unroll
        for (int cg = 0; cg < 2; ++cg) acc2[ii][cg] = (f32x4)0.0f;

#pragma unroll
    for (int q = 0; q < 9; ++q) {
        __builtin_amdgcn_s_barrier();           // A: ping-pong buf free
        if (q < 8) {
            const int jj = q + 1;
            if (jj < 8) {
                const int c = jj >> 1;
                if ((jj & 1) == 0)
                    stage_tile<128, 512>(W1t, c * 128, 512, 128, 0, sW[jj & 1], tid);
                else
                    stage_tile<128, 512>(W2t, 0, 128, DFF, c * 128, sW[jj & 1], tid);
            } else {
                stage_tile<128, 512>(Wnt, 0, 128, DM, 0, sW[0], tid);
            }
            WAITVM(4);                          // chunk q landed, q+1 in flight
        } else {
            WAITVM(0);                          // Wn landed
        }
        __builtin_amdgcn_s_barrier();           // B: all waves' DMA landed

        if (q < 8 && (q & 1) == 0) {
            // ---- G1 chunk c=q/2: H1c = prelu(ah @ W1c + b1c) -> sH ----
            const int c = q >> 1;
            f32x4 a1[2][2];
#pragma unroll
            for (int ii = 0; ii < 2; ++ii)
#pragma unroll
                for (int cg = 0; cg < 2; ++cg) a1[ii][cg] = (f32x4)0.0f;
#pragma unroll
            for (int ks = 0; ks < 4; ++ks) {
                bf16x8 bf[2];
#pragma unroll
                for (int cg = 0; cg < 2; ++cg)
                    bf[cg] = frag_ld(sW[0], wn * 32 + cg * 16 + fr, ks, g);
#pragma unroll
                for (int ii = 0; ii < 2; ++ii)
#pragma unroll
                    for (int cg = 0; cg < 2; ++cg)
                        a1[ii][cg] = __builtin_amdgcn_mfma_f32_16x16x32_bf16(
                            ah[ii][ks], bf[cg], a1[ii][cg], 0, 0, 0);
            }
#pragma unroll
            for (int ii = 0; ii < 2; ++ii)
#pragma unroll
                for (int cg = 0; cg < 2; ++cg) {
                    int colC = wn * 32 + cg * 16 + fr;
#pragma unroll
                    for (int r = 0; r < 4; ++r) {
                        int rowL = wm * 32 + ii * 16 + lr4 + r;
                        float v = a1[ii][cg][r] + bb1[c][cg];
                        v = (v >= 0.0f) ? v : aff * v;
                        int ch = (colC >> 3) ^ (rowL & 15);
                        sH[rowL * 128 + (ch << 3) + (colC & 7)] = f2bf(v);
                    }
                }
        } else if (q < 8) {
            // ---- G2 chunk c=q/2: acc2 += H1c @ W2c ----
#pragma unroll
            for (int ks = 0; ks < 4; ++ks) {
                bf16x8 af[2], bf[2];
#pragma unroll
                for (int ii = 0; ii < 2; ++ii)
                    af[ii] = frag_ld(sH, wm * 32 + ii * 16 + fr, ks, g);
#pragma unroll
                for (int cg = 0; cg < 2; ++cg)
                    bf[cg] = frag_ld(sW[1], wn * 32 + cg * 16 + fr, ks, g);
#pragma unroll
                for (int ii = 0; ii < 2; ++ii)
#pragma unroll
                    for (int cg = 0; cg < 2; ++cg)
                        acc2[ii][cg] = __builtin_amdgcn_mfma_f32_16x16x32_bf16(
                            af[ii], bf[cg], acc2[ii][cg], 0, 0, 0);
            }
        } else {
            // ---- q==8: x epilogue + optional G3 (Wn in sW[0]) ----
#pragma unroll
            for (int ii = 0; ii < 2; ++ii)
#pragma unroll
                for (int cg = 0; cg < 2; ++cg) {
                    int colL = wn * 32 + cg * 16 + fr;
#pragma unroll
                    for (int r = 0; r < 4; ++r) {
                        int rowL = wm * 32 + ii * 16 + lr4 + r;
                        int row = bm + rowL;
                        float v = acc2[ii][cg][r] + bb2[cg] + bf2f(hres[ii][cg][r]);
                        if (row < M)
                            __builtin_nontemporal_store(v, xo + (size_t)row * DM + colL);
                        if (has_next) {
                            int kc = colL >> 3;
                            sH[rowL * 128 + ((kc ^ (rowL & 15)) << 3) + (colL & 7)]
                                = f2bf(v);
                        }
                    }
                }
            if (has_next) {
                WAITLGKM0;
                __builtin_amdgcn_s_barrier();
                f32x4 a3[2][2];
#pragma unroll
                for (int ii = 0; ii < 2; ++ii)
#pragma unroll
                    for (int cg = 0; cg < 2; ++cg) a3[ii][cg] = (f32x4)0.0f;
#pragma unroll
                for (int ks = 0; ks < 4; ++ks) {
                    bf16x8 af[2], bf[2];
#pragma unroll
                    for (int ii = 0; ii < 2; ++ii)
                        af[ii] = frag_ld(sH, wm * 32 + ii * 16 + fr, ks, g);
#pragma unroll
                    for (int cg = 0; cg < 2; ++cg)
                        bf[cg] = frag_ld(sW[0], wn * 32 + cg * 16 + fr, ks, g);
#pragma unroll
                    for (int ii = 0; ii < 2; ++ii)
#pragma unroll
                        for (int cg = 0; cg < 2; ++cg)
                            a3[ii][cg] = __builtin_amdgcn_mfma_f32_16x16x32_bf16(
                                af[ii], bf[cg], a3[ii][cg], 0, 0, 0);
                }
#pragma unroll
                for (int ii = 0; ii < 2; ++ii)
#pragma unroll
                    for (int cg = 0; cg < 2; ++cg) {
                        int colL = wn * 32 + cg * 16 + fr;
#pragma unroll
                        for (int r = 0; r < 4; ++r) {
                            int row = bm + wm * 32 + ii * 16 + lr4 + r;
                            if (row < M)
                                __builtin_nontemporal_store(
                                    f2bf(a3[ii][cg][r]),
                                    z_next + (size_t)row * DM + colL);
                        }
                    }
            }
        }
        WAITLGKM0;                              // sH/sW reads+writes retired
    }
}

// ---------------------------------------------------------------------------
// One-shot: transpose+convert W/W1/W2 for all layers + convert in_feats.
// ---------------------------------------------------------------------------
__global__ void conv_all_kernel(
    const float* __restrict__ W, const float* __restrict__ W1,
    const float* __restrict__ W2, const float* __restrict__ xin,
    short* __restrict__ Wt, short* __restrict__ W1t, short* __restrict__ W2t,
    short* __restrict__ xbf, int nFeat, int nL)
{
    int idx = blockIdx.x * blockDim.x + threadIdx.x;
    const int n0 = nL * DM * DM, n1 = nL * DM * DFF, n2 = nL * DFF * DM;
    if (idx < n0) {
        int l = idx / (DM * DM), rem = idx & (DM * DM - 1);
        int r = rem >> 7, c = rem & 127;
        Wt[(size_t)l * DM * DM + c * DM + r] = f2bf(W[idx]);
        return;
    }
    idx -= n0;
    if (idx < n1) {
        int l = idx / (DM * DFF), rem = idx & (DM * DFF - 1);
        int r = rem >> 9, c = rem & 511;
        W1t[(size_t)l * DM * DFF + (size_t)c * DM + r] = f2bf(W1[idx]);
        return;
    }
    idx -= n1;
    if (idx < n2) {
        int l = idx / (DFF * DM), rem = idx & (DFF * DM - 1);
        int r = rem >> 7, c = rem & 127;
        W2t[(size_t)l * DFF * DM + (size_t)c * DFF + r] = f2bf(W2[idx]);
        return;
    }
    idx -= n2;
    if (idx < nFeat) xbf[idx] = f2bf(xin[idx]);
}

// el/er from bf16 z
__global__ void el_er_kernel(const short* __restrict__ z,
                             const float* __restrict__ al,
                             const float* __restrict__ ar,
                             float* __restrict__ el, float* __restrict__ er, int N)
{
    int idx = blockIdx.x * blockDim.x + threadIdx.x;
    if (idx >= N * NH) return;
    int n = idx >> 3, h = idx & 7;
    const unsigned* zp = (const unsigned*)(z + (size_t)n * DM + h * 16);
    const float* alp = al + h * 16;
    const float* arp = ar + h * 16;
    float sl = 0.0f, sr = 0.0f;
#pragma unroll
    for (int d2 = 0; d2 < 8; ++d2) {
        unsigned u = zp[d2];
        float z0 = bf2f((unsigned short)(u & 0xffff));
        float z1 = bf2f((unsigned short)(u >> 16));
        sl = fmaf(z0, alp[2 * d2], sl);     sl = fmaf(z1, alp[2 * d2 + 1], sl);
        sr = fmaf(z0, arp[2 * d2], sr);     sr = fmaf(z1, arp[2 * d2 + 1], sr);
    }
    el[idx] = sl;
    er[idx] = sr;
}

// ---------------- CSR build ----------------
__global__ void hist_kernel(const int* __restrict__ dst, int* __restrict__ deg, int E)
{
    int e = blockIdx.x * blockDim.x + threadIdx.x;
    if (e < E) atomicAdd(&deg[dst[e]], 1);
}

__global__ void scan1_kernel(const int* __restrict__ deg, int* __restrict__ incl,
                             int* __restrict__ bsum, int N)
{
    __shared__ int sm[256];
    int i = blockIdx.x * 256 + threadIdx.x;
    int v = (i < N) ? deg[i] : 0;
    sm[threadIdx.x] = v;
    __syncthreads();
    for (int off = 1; off < 256; off <<= 1) {
        int t = (threadIdx.x >= off) ? sm[threadIdx.x - off] : 0;
        __syncthreads();
        sm[threadIdx.x] += t;
        __syncthreads();
    }
    if (i < N) incl[i] = sm[threadIdx.x];
    if (threadIdx.x == 255) bsum[blockIdx.x] = sm[255];
}

__global__ void scan2_kernel(int* __restrict__ bsum, int nb)
{
    __shared__ int sm[256];
    int v = (threadIdx.x < nb) ? bsum[threadIdx.x] : 0;
    sm[threadIdx.x] = v;
    __syncthreads();
    for (int off = 1; off < 256; off <<= 1) {
        int t = (threadIdx.x >= off) ? sm[threadIdx.x - off] : 0;
        __syncthreads();
        sm[threadIdx.x] += t;
        __syncthreads();
    }
    if (threadIdx.x < nb) bsum[threadIdx.x] = sm[threadIdx.x];
}

__global__ void scan3_kernel(const int* __restrict__ incl, const int* __restrict__ bsum,
                             int* __restrict__ row_ptr, int N)
{
    int i = blockIdx.x * 256 + threadIdx.x;
    if (i < N) {
        int off = (blockIdx.x > 0) ? bsum[blockIdx.x - 1] : 0;
        row_ptr[i + 1] = incl[i] + off;
    }
    if (i == 0) row_ptr[0] = 0;
}

__global__ void scatter_kernel(const int* __restrict__ src, const int* __restrict__ dst,
                               const int* __restrict__ row_ptr, int* __restrict__ cursor,
                               int* __restrict__ csr_src, int E)
{
    int e = blockIdx.x * blockDim.x + threadIdx.x;
    if (e >= E) return;
    int t = dst[e];
    int pos = atomicAdd(&cursor[t], 1);
    csr_src[row_ptr[t] + pos] = src[e];
}

// ---------------------------------------------------------------------------
// Fused: edge-softmax + aggregate + conv bias + PReLU + LN1 + LN2.
// TWO nodes per wave (32 lanes each, 8B z-loads).
// ---------------------------------------------------------------------------
__global__ __launch_bounds__(256) void gat_agg_ln_kernel(
    const int* __restrict__ row_ptr, const int* __restrict__ csr_src,
    const short* __restrict__ z, const float* __restrict__ el,
    const float* __restrict__ er, const float* __restrict__ cb,
    const float* __restrict__ a_conv,
    const float* __restrict__ scale, const float* __restrict__ bias,
    short* __restrict__ h_out, short* __restrict__ hn_out, int N)
{
    int wave = threadIdx.x >> 6, lane = threadIdx.x & 63;
    int half = lane >> 5, l32 = lane & 31;
    int t = blockIdx.x * 8 + wave * 2 + half;
    if (t >= N) return;
    int h = l32 >> 2;
    int cbase = l32 * 4;
    float er_t = er[t * NH + h];
    int e0 = row_ptr[t], e1 = row_ptr[t + 1];
    float a0 = 0.0f, a1 = 0.0f, a2 = 0.0f, a3 = 0.0f, den = 0.0f;

    int e = e0;
    int s[8];
    bool have = (e + 8 <= e1);
    if (have) {
#pragma unroll
        for (int k = 0; k < 8; ++k) s[k] = csr_src[e + k];
    }
    while (have) {
        float x[8]; uintx2 u[8];
#pragma unroll
        for (int k = 0; k < 8; ++k) x[k] = el[s[k] * NH + h];
#pragma unroll
        for (int k = 0; k < 8; ++k)
            u[k] = *(const uintx2*)(z + (size_t)s[k] * DM + cbase);
        int en = e + 8;
        bool hv2 = (en + 8 <= e1);
        int sn[8];
#pragma unroll
        for (int k = 0; k < 8; ++k) sn[k] = hv2 ? csr_src[en + k] : 0;
#pragma unroll
        for (int k = 0; k < 8; ++k) {
            float v = x[k] + er_t;
            v = (v >= 0.0f) ? v : 0.2f * v;
            float w = __expf(v);
            den += w;
            unsigned w0 = u[k][0], w1 = u[k][1];
            a0 = fmaf(w, bf2f((unsigned short)(w0 & 0xffff)), a0);
            a1 = fmaf(w, bf2f((unsigned short)(w0 >> 16)),    a1);
            a2 = fmaf(w, bf2f((unsigned short)(w1 & 0xffff)), a2);
            a3 = fmaf(w, bf2f((unsigned short)(w1 >> 16)),    a3);
        }
#pragma unroll
        for (int k = 0; k < 8; ++k) s[k] = sn[k];
        e = en; have = hv2;
    }
    for (; e + 4 <= e1; e += 4) {
        int s4[4];
#pragma unroll
        for (int k = 0; k < 4; ++k) s4[k] = csr_src[e + k];
        float x[4]; uintx2 u[4];
#pragma unroll
        for (int k = 0; k < 4; ++k) x[k] = el[s4[k] * NH + h];
#pragma unroll
        for (int k = 0; k < 4; ++k)
            u[k] = *(const uintx2*)(z + (size_t)s4[k] * DM + cbase);
#pragma unroll
        for (int k = 0; k < 4; ++k) {
            float v = x[k] + er_t;
            v = (v >= 0.0f) ? v : 0.2f * v;
            float w = __expf(v);
            den += w;
            unsigned w0 = u[k][0], w1 = u[k][1];
            a0 = fmaf(w, bf2f((unsigned short)(w0 & 0xffff)), a0);
            a1 = fmaf(w, bf2f((unsigned short)(w0 >> 16)),    a1);
            a2 = fmaf(w, bf2f((unsigned short)(w1 & 0xffff)), a2);
            a3 = fmaf(w, bf2f((unsigned short)(w1 >> 16)),    a3);
        }
    }
    for (; e < e1; ++e) {
        int sv = csr_src[e];
        float v = el[sv * NH + h] + er_t;
        v = (v >= 0.0f) ? v : 0.2f * v;
        float w = __expf(v);
        den += w;
        uintx2 u = *(const uintx2*)(z + (size_t)sv * DM + cbase);
        unsigned w0 = u[0], w1 = u[1];
        a0 = fmaf(w, bf2f((unsigned short)(w0 & 0xffff)), a0);
        a1 = fmaf(w, bf2f((unsigned short)(w0 >> 16)),    a1);
        a2 = fmaf(w, bf2f((unsigned short)(w1 & 0xffff)), a2);
        a3 = fmaf(w, bf2f((unsigned short)(w1 >> 16)),    a3);
    }

    float a = *a_conv;
    float inv = 1.0f / fmaxf(den, 1e-9f);
    float o[4] = { a0 * inv + cb[cbase],     a1 * inv + cb[cbase + 1],
                   a2 * inv + cb[cbase + 2], a3 * inv + cb[cbase + 3] };
#pragma unroll
    for (int j = 0; j < 4; ++j) o[j] = (o[j] >= 0.0f) ? o[j] : a * o[j];

    float sc[4], bi[4];
#pragma unroll
    for (int j = 0; j < 4; ++j) { sc[j] = scale[cbase + j]; bi[j] = bias[cbase + j]; }

    float s1 = o[0] + o[1] + o[2] + o[3];
    float ss = o[0]*o[0] + o[1]*o[1] + o[2]*o[2] + o[3]*o[3];
#pragma unroll
    for (int off = 16; off > 0; off >>= 1) {
        s1 += __shfl_xor(s1, off, 64);
        ss += __shfl_xor(ss, off, 64);
    }
    float mean = s1 * (1.0f / 128.0f);
    float var = ss * (1.0f / 128.0f) - mean * mean;
    float rstd = rsqrtf(var + 1e-5f);
    float hv[4];
#pragma unroll
    for (int j = 0; j < 4; ++j) hv[j] = (o[j] - mean) * rstd * sc[j] + bi[j];
    {
        uintx2 p;
        p[0] = (unsigned)(unsigned short)f2bf(hv[0])
             | ((unsigned)(unsigned short)f2bf(hv[1]) << 16);
        p[1] = (unsigned)(unsigned short)f2bf(hv[2])
             | ((unsigned)(unsigned short)f2bf(hv[3]) << 16);
        *(uintx2*)(h_out + (size_t)t * DM + cbase) = p;
    }

    s1 = hv[0] + hv[1] + hv[2] + hv[3];
    ss = hv[0]*hv[0] + hv[1]*hv[1] + hv[2]*hv[2] + hv[3]*hv[3];
#pragma unroll
    for (int off = 16; off > 0; off >>= 1) {
        s1 += __shfl_xor(s1, off, 64);
        ss += __shfl_xor(ss, off, 64);
    }
    mean = s1 * (1.0f / 128.0f);
    var = ss * (1.0f / 128.0f) - mean * mean;
    rstd = rsqrtf(var + 1e-5f);
    {
        uintx2 p;
        float n0 = (hv[0] - mean) * rstd * sc[0] + bi[0];
        float n1 = (hv[1] - mean) * rstd * sc[1] + bi[1];
        float n2 = (hv[2] - mean) * rstd * sc[2] + bi[2];
        float n3 = (hv[3] - mean) * rstd * sc[3] + bi[3];
        p[0] = (unsigned)(unsigned short)f2bf(n0)
             | ((unsigned)(unsigned short)f2bf(n1) << 16);
        p[1] = (unsigned)(unsigned short)f2bf(n2)
             | ((unsigned)(unsigned short)f2bf(n3) << 16);
        *(uintx2*)(hn_out + (size_t)t * DM + cbase) = p;
    }
}

extern "C" void kernel_launch(void* const* d_in, const int* in_sizes, int n_in,
                              void* d_out, int out_size, void* d_ws, size_t ws_size,
                              hipStream_t stream)
{
    const float* in_feats = (const float*)d_in[0];
    const int*   src      = (const int*)d_in[1];
    const int*   dst      = (const int*)d_in[2];
    const float* W        = (const float*)d_in[3];
    const float* attn_l   = (const float*)d_in[4];
    const float* attn_r   = (const float*)d_in[5];
    const float* convb    = (const float*)d_in[6];
    const float* a_conv   = (const float*)d_in[7];
    const float* ln_scale = (const float*)d_in[8];
    const float* ln_bias  = (const float*)d_in[9];
    const float* W1       = (const float*)d_in[10];
    const float* b1       = (const float*)d_in[11];
    const float* W2       = (const float*)d_in[12];
    const float* b2       = (const float*)d_in[13];
    const float* a_ff     = (const float*)d_in[14];
    float* out = (float*)d_out;

    const int N = in_sizes[0] / DM;
    const int E = in_sizes[1];
    const int L = in_sizes[7];

    char* wsb = (char*)d_ws;
    size_t off = 0;
    auto alloc = [&](size_t bytes) { char* p = wsb + off; off += (bytes + 255) & ~(size_t)255; return p; };

    short* z_bf  = (short*)alloc((size_t)N * DM * sizeof(short));
    short* h_bf  = (short*)alloc((size_t)N * DM * sizeof(short));
    short* hn_bf = (short*)alloc((size_t)N * DM * sizeof(short));
    short* x_bf  = (short*)alloc((size_t)N * DM * sizeof(short));
    float* el    = (float*)alloc((size_t)N * NH * sizeof(float));
    float* er    = (float*)alloc((size_t)N * NH * sizeof(float));
    short* Wt    = (short*)alloc((size_t)L * DM * DM * sizeof(short));
    short* W1t   = (short*)alloc((size_t)L * DFF * DM * sizeof(short));
    short* W2t   = (short*)alloc((size_t)L * DM * DFF * sizeof(short));
    int* deg     = (int*)alloc((size_t)N * sizeof(int));
    int* incl    = (int*)alloc((size_t)N * sizeof(int));
    int* bsum    = (int*)alloc(256 * sizeof(int));
    int* row_ptr = (int*)alloc((size_t)(N + 1) * sizeof(int));
    int* cursor  = (int*)alloc((size_t)N * sizeof(int));
    int* csr_src = (int*)alloc((size_t)E * sizeof(int));

    const int gM64  = (N + 63) / 64;
    const int nbScan = (N + 255) / 256;

    // ---- CSR by dst ----
    hipMemsetAsync(deg, 0, (size_t)N * sizeof(int), stream);
    hipMemsetAsync(cursor, 0, (size_t)N * sizeof(int), stream);
    hist_kernel<<<(E + 255) / 256, 256, 0, stream>>>(dst, deg, E);
    scan1_kernel<<<nbScan, 256, 0, stream>>>(deg, incl, bsum, N);
    scan2_kernel<<<1, 256, 0, stream>>>(bsum, nbScan);
    scan3_kernel<<<nbScan, 256, 0, stream>>>(incl, bsum, row_ptr, N);
    scatter_kernel<<<(E + 255) / 256, 256, 0, stream>>>(src, dst, row_ptr, cursor, csr_src, E);

    // ---- all weight conversions + input convert in one kernel ----
    {
        int total = L * DM * DM + L * DM * DFF + L * DFF * DM + N * DM;
        conv_all_kernel<<<(total + 255) / 256, 256, 0, stream>>>(
            W, W1, W2, in_feats, Wt, W1t, W2t, x_bf, N * DM, L);
    }

    // layer-0 z projection: z = x @ W[0]
    gemm_k128_stream<false, DM><<<dim3(1, 512), 512, 0, stream>>>(
        x_bf, Wt, nullptr, nullptr, N, z_bf);
    el_er_kernel<<<(N * NH + 255) / 256, 256, 0, stream>>>(
        z_bf, attn_l, attn_r, el, er, N);

    for (int l = 0; l < L; ++l) {
        float* xo = out + (size_t)l * N * DM;
        const int has_next = (l + 1 < L) ? 1 : 0;
        const short* Wnt = has_next ? (Wt + (size_t)(l + 1) * DM * DM) : Wt;

        gat_agg_ln_kernel<<<(N + 7) / 8, 256, 0, stream>>>(
            row_ptr, csr_src, z_bf, el, er, convb + (size_t)l * DM, a_conv + l,
            ln_scale + (size_t)l * DM, ln_bias + (size_t)l * DM, h_bf, hn_bf, N);

        // xo = prelu(hn@W1+b1)@W2 + b2 + h ; z_bf = bf16(xo)@W[l+1]  (one kernel)
        ffn12z<<<gM64, 512, 0, stream>>>(
            hn_bf, W1t + (size_t)l * DFF * DM, W2t + (size_t)l * DM * DFF,
            h_bf, b1 + (size_t)l * DFF, b2 + (size_t)l * DM, a_ff + l,
            Wnt, has_next, N, xo, z_bf);

        if (has_next)
            el_er_kernel<<<(N * NH + 255) / 256, 256, 0, stream>>>(
                z_bf, attn_l + (size_t)(l + 1) * NH * 16,
                attn_r + (size_t)(l + 1) * NH * 16, el, er, N);
    }
}

// Round 8
// 454.765 us; speedup vs baseline: 1.3356x; 1.3356x over previous
//
#include <hip/hip_runtime.h>

#define DM 128
#define NH 8
#define DFF 512

typedef __attribute__((ext_vector_type(8))) short bf16x8;
typedef __attribute__((ext_vector_type(4))) float f32x4;
typedef __attribute__((ext_vector_type(2))) unsigned uintx2;

#define WAITVM(N) do { asm volatile("s_waitcnt vmcnt(" #N ")" ::: "memory"); \
                       __builtin_amdgcn_sched_barrier(0); } while (0)
#define WAITLGKM0 do { asm volatile("s_waitcnt lgkmcnt(0)" ::: "memory"); \
                       __builtin_amdgcn_sched_barrier(0); } while (0)

__device__ __forceinline__ short f2bf(float f) {
    union { float f; unsigned u; } v; v.f = f;
    unsigned r = v.u + 0x7fffu + ((v.u >> 16) & 1u);   // RNE
    return (short)(r >> 16);
}
__device__ __forceinline__ float bf2f(unsigned short b) {
    union { unsigned u; float f; } v; v.u = ((unsigned)b) << 16; return v.f;
}

// ---------------------------------------------------------------------------
// Async-stage a [ROWS x 128] bf16 tile into LDS via global_load_lds (16B/lane).
// LDS linear [row][128 shorts]; 16B chunk index XOR-swizzled on the GLOBAL
// side: LDS (row, kc) holds global (row, kc^(row&15)). Readers use same XOR.
// Ops per thread = ROWS*16/NT.
// ---------------------------------------------------------------------------
template<int ROWS, int NT>
__device__ __forceinline__ void stage_tile(
    const short* __restrict__ g, int row0, int maxrow, int rstride, int kbase,
    short* s, int tid)
{
    const int lane = tid & 63;
#pragma unroll
    for (int rr = 0; rr < ROWS * 16 / NT; ++rr) {
        int idx = rr * NT + tid;                    // 16B-chunk index in tile
        int row = idx >> 4, kc = idx & 15;
        int rg = row0 + row;
        rg = (rg < maxrow) ? rg : (maxrow - 1);
        const short* src = g + (size_t)rg * rstride + kbase
                         + ((kc ^ (row & 15)) << 3);
        short* dst = s + (size_t)(idx - lane) * 8;  // wave-uniform base
        __builtin_amdgcn_global_load_lds(
            (const __attribute__((address_space(1))) void*)src,
            (__attribute__((address_space(3))) void*)dst, 16, 0, 0);
    }
}

// MFMA fragment read from a swizzled [*][128] tile (row stride 128 shorts).
__device__ __forceinline__ bf16x8 frag_ld(const short* s, int row, int ks, int g)
{
    return *(const bf16x8*)(s + row * 128 + ((((ks << 2) + g) ^ (row & 15)) << 3));
}

// ---------------------------------------------------------------------------
// Weight-stationary streaming GEMM, K=128 (layer-0 z projection):
//   out[t*64.., 0..127] = A[64,128] @ Bt[128,128]^T
// 512 thr = 8 waves as 2 row x 4 col (32x32 wave tiles).
// ---------------------------------------------------------------------------
template<bool PRELU, int NOUT>
__global__ __launch_bounds__(512, 4) void gemm_k128_stream(
    const short* __restrict__ A, const short* __restrict__ Bt,
    const float* __restrict__ bias, const float* __restrict__ affp,
    int M, short* __restrict__ outbf)
{
    __shared__ __align__(16) short sW[128 * 128];      // 32 KB
    __shared__ __align__(16) short sA[3][64 * 128];    // 3 x 16 KB

    const int tid = threadIdx.x;
    const int wave = tid >> 6, lane = tid & 63;
    const int wm = wave >> 2, wn = wave & 3;
    const int bn = blockIdx.x * 128;
    const int fr = lane & 15, g = lane >> 4;
    const int lr4 = g << 2;
    const int nT = (M + 63) >> 6;
    const int GY = gridDim.y;
    const int t0 = blockIdx.y;
    const int nLoc = (t0 < nT) ? ((nT - 1 - t0) / GY + 1) : 0;

    float bb[2]; float aff = 0.0f;
    if constexpr (PRELU) {
        aff = *affp;
#pragma unroll
        for (int cg = 0; cg < 2; ++cg)
            bb[cg] = bias[bn + wn * 32 + cg * 16 + fr];
    }

    stage_tile<128, 512>(Bt + (size_t)bn * 128, 0, 128, 128, 0, sW, tid);
    if (nLoc > 0) stage_tile<64, 512>(A, t0 * 64, M, 128, 0, sA[0], tid);
    if (nLoc > 1) stage_tile<64, 512>(A, (t0 + GY) * 64, M, 128, 0, sA[1], tid);

    for (int i = 0; i < nLoc; ++i) {
        const int t = t0 + i * GY;
        if (i >= 1 && i + 1 < nLoc)
            stage_tile<64, 512>(A, (t + GY) * 64, M, 128, 0, sA[(i + 1) % 3], tid);

        if (i == 0) { if (nLoc > 1) { WAITVM(2); } else { WAITVM(0); } }
        else if (i + 1 < nLoc) { WAITVM(18); }
        else { WAITVM(16); }
        __builtin_amdgcn_s_barrier();

        const short* sAb = sA[i % 3];
        f32x4 acc[2][2];
#pragma unroll
        for (int ii = 0; ii < 2; ++ii)
#pragma unroll
            for (int cg = 0; cg < 2; ++cg) acc[ii][cg] = (f32x4)0.0f;

#pragma unroll
        for (int ks = 0; ks < 4; ++ks) {
            bf16x8 af[2], bf[2];
#pragma unroll
            for (int ii = 0; ii < 2; ++ii)
                af[ii] = frag_ld(sAb, wm * 32 + ii * 16 + fr, ks, g);
#pragma unroll
            for (int cg = 0; cg < 2; ++cg)
                bf[cg] = frag_ld(sW, wn * 32 + cg * 16 + fr, ks, g);
#pragma unroll
            for (int ii = 0; ii < 2; ++ii)
#pragma unroll
                for (int cg = 0; cg < 2; ++cg)
                    acc[ii][cg] = __builtin_amdgcn_mfma_f32_16x16x32_bf16(
                        af[ii], bf[cg], acc[ii][cg], 0, 0, 0);
        }

#pragma unroll
        for (int ii = 0; ii < 2; ++ii)
#pragma unroll
            for (int cg = 0; cg < 2; ++cg) {
                int colL = wn * 32 + cg * 16 + fr;
#pragma unroll
                for (int r = 0; r < 4; ++r) {
                    int row = t * 64 + wm * 32 + ii * 16 + lr4 + r;
                    if (row < M) {
                        float v = acc[ii][cg][r];
                        if constexpr (PRELU) {
                            v += bb[cg];
                            v = (v >= 0.0f) ? v : aff * v;
                        }
                        outbf[(size_t)row * NOUT + bn + colL] = f2bf(v);
                    }
                }
            }
    }
}

// ---------------------------------------------------------------------------
// Fully fused FFN + next-layer z projection, chunk-interleaved (no H1 tile):
//   for c in 0..3: H1c = prelu(hn @ W1t[c] + b1[c]) -> sH (16 KB);
//                  acc2 += H1c @ W2t[:,c]
//   x = acc2 + b2 + h -> xo (fp32);  z_next = bf16(x) @ Wnt^T
// Weight stream = 9 chunks through a 2x32KB ping-pong, counted vmcnt(4).
// __launch_bounds__(512,2): 256-VGPR cap -> NO SPILLS (R6/R7's (512,4) cap
// of 64 VGPRs spilled ~190 MB of scratch traffic to HBM). Occupancy is
// LDS-bound at 2 blocks/CU (80 KB) either way.
// ---------------------------------------------------------------------------
__global__ __launch_bounds__(512, 2) void ffn12z(
    const short* __restrict__ hn, const short* __restrict__ W1t,
    const short* __restrict__ W2t, const short* __restrict__ h_bf,
    const float* __restrict__ b1, const float* __restrict__ b2,
    const float* __restrict__ affp, const short* __restrict__ Wnt,
    int has_next, int M, float* __restrict__ xo, short* __restrict__ z_next)
{
    __shared__ __align__(16) short sW[2][128 * 128];   // 2 x 32 KB weights
    __shared__ __align__(16) short sH[64 * 128];       // 16 KB H1-chunk / x

    const int tid = threadIdx.x;
    const int wave = tid >> 6, lane = tid & 63;
    const int wm = wave >> 2, wn = wave & 3;
    const int bm = blockIdx.x * 64;
    const int fr = lane & 15, g = lane >> 4;
    const int lr4 = g << 2, fk8 = g << 3;

    // ---- prologue: ALL global loads issued here, then chunk 0 ----
    bf16x8 ah[2][4];
#pragma unroll
    for (int ii = 0; ii < 2; ++ii) {
        int row = bm + wm * 32 + ii * 16 + fr;
        row = (row < M) ? row : (M - 1);
#pragma unroll
        for (int ks = 0; ks < 4; ++ks)
            ah[ii][ks] = *(const bf16x8*)(hn + (size_t)row * DM + ks * 32 + fk8);
    }
    unsigned short hres[2][2][4];
    float bb2[2];
#pragma unroll
    for (int ii = 0; ii < 2; ++ii)
#pragma unroll
        for (int cg = 0; cg < 2; ++cg) {
            int colL = wn * 32 + cg * 16 + fr;
            if (ii == 0) bb2[cg] = b2[colL];
#pragma unroll
            for (int r = 0; r < 4; ++r) {
                int row = bm + wm * 32 + ii * 16 + lr4 + r;
                int rc = (row < M) ? row : (M - 1);
                hres[ii][cg][r] = *(const unsigned short*)(h_bf + (size_t)rc * DM + colL);
            }
        }
    float bb1[4][2];
#pragma unroll
    for (int c = 0; c < 4; ++c)
#pragma unroll
        for (int cg = 0; cg < 2; ++cg)
            bb1[c][cg] = b1[c * 128 + wn * 32 + cg * 16 + fr];
    float aff = *affp;

    stage_tile<128, 512>(W1t, 0, 512, 128, 0, sW[0], tid);   // chunk 0

    f32x4 acc2[2][2];
#pragma unroll
    for (int ii = 0; ii < 2; ++ii)
#pragma unroll
        for (int cg = 0; cg < 2; ++cg) acc2[ii][cg] = (f32x4)0.0f;

#pragma unroll
    for (int q = 0; q < 9; ++q) {
        __builtin_amdgcn_s_barrier();           // A: ping-pong buf free
        if (q < 8) {
            const int jj = q + 1;
            if (jj < 8) {
                const int c = jj >> 1;
                if ((jj & 1) == 0)
                    stage_tile<128, 512>(W1t, c * 128, 512, 128, 0, sW[jj & 1], tid);
                else
                    stage_tile<128, 512>(W2t, 0, 128, DFF, c * 128, sW[jj & 1], tid);
            } else {
                stage_tile<128, 512>(Wnt, 0, 128, DM, 0, sW[0], tid);
            }
            WAITVM(4);                          // chunk q landed, q+1 in flight
        } else {
            WAITVM(0);                          // Wn landed
        }
        __builtin_amdgcn_s_barrier();           // B: all waves' DMA landed

        if (q < 8 && (q & 1) == 0) {
            // ---- G1 chunk c=q/2: H1c = prelu(ah @ W1c + b1c) -> sH ----
            const int c = q >> 1;
            f32x4 a1[2][2];
#pragma unroll
            for (int ii = 0; ii < 2; ++ii)
#pragma unroll
                for (int cg = 0; cg < 2; ++cg) a1[ii][cg] = (f32x4)0.0f;
#pragma unroll
            for (int ks = 0; ks < 4; ++ks) {
                bf16x8 bf[2];
#pragma unroll
                for (int cg = 0; cg < 2; ++cg)
                    bf[cg] = frag_ld(sW[0], wn * 32 + cg * 16 + fr, ks, g);
#pragma unroll
                for (int ii = 0; ii < 2; ++ii)
#pragma unroll
                    for (int cg = 0; cg < 2; ++cg)
                        a1[ii][cg] = __builtin_amdgcn_mfma_f32_16x16x32_bf16(
                            ah[ii][ks], bf[cg], a1[ii][cg], 0, 0, 0);
            }
#pragma unroll
            for (int ii = 0; ii < 2; ++ii)
#pragma unroll
                for (int cg = 0; cg < 2; ++cg) {
                    int colC = wn * 32 + cg * 16 + fr;
#pragma unroll
                    for (int r = 0; r < 4; ++r) {
                        int rowL = wm * 32 + ii * 16 + lr4 + r;
                        float v = a1[ii][cg][r] + bb1[c][cg];
                        v = (v >= 0.0f) ? v : aff * v;
                        int ch = (colC >> 3) ^ (rowL & 15);
                        sH[rowL * 128 + (ch << 3) + (colC & 7)] = f2bf(v);
                    }
                }
        } else if (q < 8) {
            // ---- G2 chunk c=q/2: acc2 += H1c @ W2c ----
#pragma unroll
            for (int ks = 0; ks < 4; ++ks) {
                bf16x8 af[2], bf[2];
#pragma unroll
                for (int ii = 0; ii < 2; ++ii)
                    af[ii] = frag_ld(sH, wm * 32 + ii * 16 + fr, ks, g);
#pragma unroll
                for (int cg = 0; cg < 2; ++cg)
                    bf[cg] = frag_ld(sW[1], wn * 32 + cg * 16 + fr, ks, g);
#pragma unroll
                for (int ii = 0; ii < 2; ++ii)
#pragma unroll
                    for (int cg = 0; cg < 2; ++cg)
                        acc2[ii][cg] = __builtin_amdgcn_mfma_f32_16x16x32_bf16(
                            af[ii], bf[cg], acc2[ii][cg], 0, 0, 0);
            }
        } else {
            // ---- q==8: x epilogue + optional G3 (Wn in sW[0]) ----
#pragma unroll
            for (int ii = 0; ii < 2; ++ii)
#pragma unroll
                for (int cg = 0; cg < 2; ++cg) {
                    int colL = wn * 32 + cg * 16 + fr;
#pragma unroll
                    for (int r = 0; r < 4; ++r) {
                        int rowL = wm * 32 + ii * 16 + lr4 + r;
                        int row = bm + rowL;
                        float v = acc2[ii][cg][r] + bb2[cg] + bf2f(hres[ii][cg][r]);
                        if (row < M) xo[(size_t)row * DM + colL] = v;
                        if (has_next) {
                            int kc = colL >> 3;
                            sH[rowL * 128 + ((kc ^ (rowL & 15)) << 3) + (colL & 7)]
                                = f2bf(v);
                        }
                    }
                }
            if (has_next) {
                WAITLGKM0;
                __builtin_amdgcn_s_barrier();
                f32x4 a3[2][2];
#pragma unroll
                for (int ii = 0; ii < 2; ++ii)
#pragma unroll
                    for (int cg = 0; cg < 2; ++cg) a3[ii][cg] = (f32x4)0.0f;
#pragma unroll
                for (int ks = 0; ks < 4; ++ks) {
                    bf16x8 af[2], bf[2];
#pragma unroll
                    for (int ii = 0; ii < 2; ++ii)
                        af[ii] = frag_ld(sH, wm * 32 + ii * 16 + fr, ks, g);
#pragma unroll
                    for (int cg = 0; cg < 2; ++cg)
                        bf[cg] = frag_ld(sW[0], wn * 32 + cg * 16 + fr, ks, g);
#pragma unroll
                    for (int ii = 0; ii < 2; ++ii)
#pragma unroll
                        for (int cg = 0; cg < 2; ++cg)
                            a3[ii][cg] = __builtin_amdgcn_mfma_f32_16x16x32_bf16(
                                af[ii], bf[cg], a3[ii][cg], 0, 0, 0);
                }
#pragma unroll
                for (int ii = 0; ii < 2; ++ii)
#pragma unroll
                    for (int cg = 0; cg < 2; ++cg) {
                        int colL = wn * 32 + cg * 16 + fr;
#pragma unroll
                        for (int r = 0; r < 4; ++r) {
                            int row = bm + wm * 32 + ii * 16 + lr4 + r;
                            if (row < M)
                                z_next[(size_t)row * DM + colL] = f2bf(a3[ii][cg][r]);
                        }
                    }
            }
        }
        WAITLGKM0;                              // sH/sW reads+writes retired
    }
}

// ---------------------------------------------------------------------------
// One-shot: transpose+convert W/W1/W2 for all layers + convert in_feats.
// ---------------------------------------------------------------------------
__global__ void conv_all_kernel(
    const float* __restrict__ W, const float* __restrict__ W1,
    const float* __restrict__ W2, const float* __restrict__ xin,
    short* __restrict__ Wt, short* __restrict__ W1t, short* __restrict__ W2t,
    short* __restrict__ xbf, int nFeat, int nL)
{
    int idx = blockIdx.x * blockDim.x + threadIdx.x;
    const int n0 = nL * DM * DM, n1 = nL * DM * DFF, n2 = nL * DFF * DM;
    if (idx < n0) {
        int l = idx / (DM * DM), rem = idx & (DM * DM - 1);
        int r = rem >> 7, c = rem & 127;
        Wt[(size_t)l * DM * DM + c * DM + r] = f2bf(W[idx]);
        return;
    }
    idx -= n0;
    if (idx < n1) {
        int l = idx / (DM * DFF), rem = idx & (DM * DFF - 1);
        int r = rem >> 9, c = rem & 511;
        W1t[(size_t)l * DM * DFF + (size_t)c * DM + r] = f2bf(W1[idx]);
        return;
    }
    idx -= n1;
    if (idx < n2) {
        int l = idx / (DFF * DM), rem = idx & (DFF * DM - 1);
        int r = rem >> 7, c = rem & 127;
        W2t[(size_t)l * DFF * DM + (size_t)c * DFF + r] = f2bf(W2[idx]);
        return;
    }
    idx -= n2;
    if (idx < nFeat) xbf[idx] = f2bf(xin[idx]);
}

// el/er from bf16 z
__global__ void el_er_kernel(const short* __restrict__ z,
                             const float* __restrict__ al,
                             const float* __restrict__ ar,
                             float* __restrict__ el, float* __restrict__ er, int N)
{
    int idx = blockIdx.x * blockDim.x + threadIdx.x;
    if (idx >= N * NH) return;
    int n = idx >> 3, h = idx & 7;
    const unsigned* zp = (const unsigned*)(z + (size_t)n * DM + h * 16);
    const float* alp = al + h * 16;
    const float* arp = ar + h * 16;
    float sl = 0.0f, sr = 0.0f;
#pragma unroll
    for (int d2 = 0; d2 < 8; ++d2) {
        unsigned u = zp[d2];
        float z0 = bf2f((unsigned short)(u & 0xffff));
        float z1 = bf2f((unsigned short)(u >> 16));
        sl = fmaf(z0, alp[2 * d2], sl);     sl = fmaf(z1, alp[2 * d2 + 1], sl);
        sr = fmaf(z0, arp[2 * d2], sr);     sr = fmaf(z1, arp[2 * d2 + 1], sr);
    }
    el[idx] = sl;
    er[idx] = sr;
}

// ---------------- CSR build ----------------
__global__ void hist_kernel(const int* __restrict__ dst, int* __restrict__ deg, int E)
{
    int e = blockIdx.x * blockDim.x + threadIdx.x;
    if (e < E) atomicAdd(&deg[dst[e]], 1);
}

__global__ void scan1_kernel(const int* __restrict__ deg, int* __restrict__ incl,
                             int* __restrict__ bsum, int N)
{
    __shared__ int sm[256];
    int i = blockIdx.x * 256 + threadIdx.x;
    int v = (i < N) ? deg[i] : 0;
    sm[threadIdx.x] = v;
    __syncthreads();
    for (int off = 1; off < 256; off <<= 1) {
        int t = (threadIdx.x >= off) ? sm[threadIdx.x - off] : 0;
        __syncthreads();
        sm[threadIdx.x] += t;
        __syncthreads();
    }
    if (i < N) incl[i] = sm[threadIdx.x];
    if (threadIdx.x == 255) bsum[blockIdx.x] = sm[255];
}

__global__ void scan2_kernel(int* __restrict__ bsum, int nb)
{
    __shared__ int sm[256];
    int v = (threadIdx.x < nb) ? bsum[threadIdx.x] : 0;
    sm[threadIdx.x] = v;
    __syncthreads();
    for (int off = 1; off < 256; off <<= 1) {
        int t = (threadIdx.x >= off) ? sm[threadIdx.x - off] : 0;
        __syncthreads();
        sm[threadIdx.x] += t;
        __syncthreads();
    }
    if (threadIdx.x < nb) bsum[threadIdx.x] = sm[threadIdx.x];
}

__global__ void scan3_kernel(const int* __restrict__ incl, const int* __restrict__ bsum,
                             int* __restrict__ row_ptr, int N)
{
    int i = blockIdx.x * 256 + threadIdx.x;
    if (i < N) {
        int off = (blockIdx.x > 0) ? bsum[blockIdx.x - 1] : 0;
        row_ptr[i + 1] = incl[i] + off;
    }
    if (i == 0) row_ptr[0] = 0;
}

__global__ void scatter_kernel(const int* __restrict__ src, const int* __restrict__ dst,
                               const int* __restrict__ row_ptr, int* __restrict__ cursor,
                               int* __restrict__ csr_src, int E)
{
    int e = blockIdx.x * blockDim.x + threadIdx.x;
    if (e >= E) return;
    int t = dst[e];
    int pos = atomicAdd(&cursor[t], 1);
    csr_src[row_ptr[t] + pos] = src[e];
}

// ---------------------------------------------------------------------------
// Fused: edge-softmax + aggregate + conv bias + PReLU + LN1 + LN2.
// TWO nodes per wave (32 lanes each, 8B z-loads).
// ---------------------------------------------------------------------------
__global__ __launch_bounds__(256) void gat_agg_ln_kernel(
    const int* __restrict__ row_ptr, const int* __restrict__ csr_src,
    const short* __restrict__ z, const float* __restrict__ el,
    const float* __restrict__ er, const float* __restrict__ cb,
    const float* __restrict__ a_conv,
    const float* __restrict__ scale, const float* __restrict__ bias,
    short* __restrict__ h_out, short* __restrict__ hn_out, int N)
{
    int wave = threadIdx.x >> 6, lane = threadIdx.x & 63;
    int half = lane >> 5, l32 = lane & 31;
    int t = blockIdx.x * 8 + wave * 2 + half;
    if (t >= N) return;
    int h = l32 >> 2;
    int cbase = l32 * 4;
    float er_t = er[t * NH + h];
    int e0 = row_ptr[t], e1 = row_ptr[t + 1];
    float a0 = 0.0f, a1 = 0.0f, a2 = 0.0f, a3 = 0.0f, den = 0.0f;

    int e = e0;
    int s[8];
    bool have = (e + 8 <= e1);
    if (have) {
#pragma unroll
        for (int k = 0; k < 8; ++k) s[k] = csr_src[e + k];
    }
    while (have) {
        float x[8]; uintx2 u[8];
#pragma unroll
        for (int k = 0; k < 8; ++k) x[k] = el[s[k] * NH + h];
#pragma unroll
        for (int k = 0; k < 8; ++k)
            u[k] = *(const uintx2*)(z + (size_t)s[k] * DM + cbase);
        int en = e + 8;
        bool hv2 = (en + 8 <= e1);
        int sn[8];
#pragma unroll
        for (int k = 0; k < 8; ++k) sn[k] = hv2 ? csr_src[en + k] : 0;
#pragma unroll
        for (int k = 0; k < 8; ++k) {
            float v = x[k] + er_t;
            v = (v >= 0.0f) ? v : 0.2f * v;
            float w = __expf(v);
            den += w;
            unsigned w0 = u[k][0], w1 = u[k][1];
            a0 = fmaf(w, bf2f((unsigned short)(w0 & 0xffff)), a0);
            a1 = fmaf(w, bf2f((unsigned short)(w0 >> 16)),    a1);
            a2 = fmaf(w, bf2f((unsigned short)(w1 & 0xffff)), a2);
            a3 = fmaf(w, bf2f((unsigned short)(w1 >> 16)),    a3);
        }
#pragma unroll
        for (int k = 0; k < 8; ++k) s[k] = sn[k];
        e = en; have = hv2;
    }
    for (; e + 4 <= e1; e += 4) {
        int s4[4];
#pragma unroll
        for (int k = 0; k < 4; ++k) s4[k] = csr_src[e + k];
        float x[4]; uintx2 u[4];
#pragma unroll
        for (int k = 0; k < 4; ++k) x[k] = el[s4[k] * NH + h];
#pragma unroll
        for (int k = 0; k < 4; ++k)
            u[k] = *(const uintx2*)(z + (size_t)s4[k] * DM + cbase);
#pragma unroll
        for (int k = 0; k < 4; ++k) {
            float v = x[k] + er_t;
            v = (v >= 0.0f) ? v : 0.2f * v;
            float w = __expf(v);
            den += w;
            unsigned w0 = u[k][0], w1 = u[k][1];
            a0 = fmaf(w, bf2f((unsigned short)(w0 & 0xffff)), a0);
            a1 = fmaf(w, bf2f((unsigned short)(w0 >> 16)),    a1);
            a2 = fmaf(w, bf2f((unsigned short)(w1 & 0xffff)), a2);
            a3 = fmaf(w, bf2f((unsigned short)(w1 >> 16)),    a3);
        }
    }
    for (; e < e1; ++e) {
        int sv = csr_src[e];
        float v = el[sv * NH + h] + er_t;
        v = (v >= 0.0f) ? v : 0.2f * v;
        float w = __expf(v);
        den += w;
        uintx2 u = *(const uintx2*)(z + (size_t)sv * DM + cbase);
        unsigned w0 = u[0], w1 = u[1];
        a0 = fmaf(w, bf2f((unsigned short)(w0 & 0xffff)), a0);
        a1 = fmaf(w, bf2f((unsigned short)(w0 >> 16)),    a1);
        a2 = fmaf(w, bf2f((unsigned short)(w1 & 0xffff)), a2);
        a3 = fmaf(w, bf2f((unsigned short)(w1 >> 16)),    a3);
    }

    float a = *a_conv;
    float inv = 1.0f / fmaxf(den, 1e-9f);
    float o[4] = { a0 * inv + cb[cbase],     a1 * inv + cb[cbase + 1],
                   a2 * inv + cb[cbase + 2], a3 * inv + cb[cbase + 3] };
#pragma unroll
    for (int j = 0; j < 4; ++j) o[j] = (o[j] >= 0.0f) ? o[j] : a * o[j];

    float sc[4], bi[4];
#pragma unroll
    for (int j = 0; j < 4; ++j) { sc[j] = scale[cbase + j]; bi[j] = bias[cbase + j]; }

    float s1 = o[0] + o[1] + o[2] + o[3];
    float ss = o[0]*o[0] + o[1]*o[1] + o[2]*o[2] + o[3]*o[3];
#pragma unroll
    for (int off = 16; off > 0; off >>= 1) {
        s1 += __shfl_xor(s1, off, 64);
        ss += __shfl_xor(ss, off, 64);
    }
    float mean = s1 * (1.0f / 128.0f);
    float var = ss * (1.0f / 128.0f) - mean * mean;
    float rstd = rsqrtf(var + 1e-5f);
    float hv[4];
#pragma unroll
    for (int j = 0; j < 4; ++j) hv[j] = (o[j] - mean) * rstd * sc[j] + bi[j];
    {
        uintx2 p;
        p[0] = (unsigned)(unsigned short)f2bf(hv[0])
             | ((unsigned)(unsigned short)f2bf(hv[1]) << 16);
        p[1] = (unsigned)(unsigned short)f2bf(hv[2])
             | ((unsigned)(unsigned short)f2bf(hv[3]) << 16);
        *(uintx2*)(h_out + (size_t)t * DM + cbase) = p;
    }

    s1 = hv[0] + hv[1] + hv[2] + hv[3];
    ss = hv[0]*hv[0] + hv[1]*hv[1] + hv[2]*hv[2] + hv[3]*hv[3];
#pragma unroll
    for (int off = 16; off > 0; off >>= 1) {
        s1 += __shfl_xor(s1, off, 64);
        ss += __shfl_xor(ss, off, 64);
    }
    mean = s1 * (1.0f / 128.0f);
    var = ss * (1.0f / 128.0f) - mean * mean;
    rstd = rsqrtf(var + 1e-5f);
    {
        uintx2 p;
        float n0 = (hv[0] - mean) * rstd * sc[0] + bi[0];
        float n1 = (hv[1] - mean) * rstd * sc[1] + bi[1];
        float n2 = (hv[2] - mean) * rstd * sc[2] + bi[2];
        float n3 = (hv[3] - mean) * rstd * sc[3] + bi[3];
        p[0] = (unsigned)(unsigned short)f2bf(n0)
             | ((unsigned)(unsigned short)f2bf(n1) << 16);
        p[1] = (unsigned)(unsigned short)f2bf(n2)
             | ((unsigned)(unsigned short)f2bf(n3) << 16);
        *(uintx2*)(hn_out + (size_t)t * DM + cbase) = p;
    }
}

extern "C" void kernel_launch(void* const* d_in, const int* in_sizes, int n_in,
                              void* d_out, int out_size, void* d_ws, size_t ws_size,
                              hipStream_t stream)
{
    const float* in_feats = (const float*)d_in[0];
    const int*   src      = (const int*)d_in[1];
    const int*   dst      = (const int*)d_in[2];
    const float* W        = (const float*)d_in[3];
    const float* attn_l   = (const float*)d_in[4];
    const float* attn_r   = (const float*)d_in[5];
    const float* convb    = (const float*)d_in[6];
    const float* a_conv   = (const float*)d_in[7];
    const float* ln_scale = (const float*)d_in[8];
    const float* ln_bias  = (const float*)d_in[9];
    const float* W1       = (const float*)d_in[10];
    const float* b1       = (const float*)d_in[11];
    const float* W2       = (const float*)d_in[12];
    const float* b2       = (const float*)d_in[13];
    const float* a_ff     = (const float*)d_in[14];
    float* out = (float*)d_out;

    const int N = in_sizes[0] / DM;
    const int E = in_sizes[1];
    const int L = in_sizes[7];

    char* wsb = (char*)d_ws;
    size_t off = 0;
    auto alloc = [&](size_t bytes) { char* p = wsb + off; off += (bytes + 255) & ~(size_t)255; return p; };

    short* z_bf  = (short*)alloc((size_t)N * DM * sizeof(short));
    short* h_bf  = (short*)alloc((size_t)N * DM * sizeof(short));
    short* hn_bf = (short*)alloc((size_t)N * DM * sizeof(short));
    short* x_bf  = (short*)alloc((size_t)N * DM * sizeof(short));
    float* el    = (float*)alloc((size_t)N * NH * sizeof(float));
    float* er    = (float*)alloc((size_t)N * NH * sizeof(float));
    short* Wt    = (short*)alloc((size_t)L * DM * DM * sizeof(short));
    short* W1t   = (short*)alloc((size_t)L * DFF * DM * sizeof(short));
    short* W2t   = (short*)alloc((size_t)L * DM * DFF * sizeof(short));
    int* deg     = (int*)alloc((size_t)N * sizeof(int));
    int* incl    = (int*)alloc((size_t)N * sizeof(int));
    int* bsum    = (int*)alloc(256 * sizeof(int));
    int* row_ptr = (int*)alloc((size_t)(N + 1) * sizeof(int));
    int* cursor  = (int*)alloc((size_t)N * sizeof(int));
    int* csr_src = (int*)alloc((size_t)E * sizeof(int));

    const int gM64  = (N + 63) / 64;
    const int nbScan = (N + 255) / 256;

    // ---- CSR by dst ----
    hipMemsetAsync(deg, 0, (size_t)N * sizeof(int), stream);
    hipMemsetAsync(cursor, 0, (size_t)N * sizeof(int), stream);
    hist_kernel<<<(E + 255) / 256, 256, 0, stream>>>(dst, deg, E);
    scan1_kernel<<<nbScan, 256, 0, stream>>>(deg, incl, bsum, N);
    scan2_kernel<<<1, 256, 0, stream>>>(bsum, nbScan);
    scan3_kernel<<<nbScan, 256, 0, stream>>>(incl, bsum, row_ptr, N);
    scatter_kernel<<<(E + 255) / 256, 256, 0, stream>>>(src, dst, row_ptr, cursor, csr_src, E);

    // ---- all weight conversions + input convert in one kernel ----
    {
        int total = L * DM * DM + L * DM * DFF + L * DFF * DM + N * DM;
        conv_all_kernel<<<(total + 255) / 256, 256, 0, stream>>>(
            W, W1, W2, in_feats, Wt, W1t, W2t, x_bf, N * DM, L);
    }

    // layer-0 z projection: z = x @ W[0]
    gemm_k128_stream<false, DM><<<dim3(1, 512), 512, 0, stream>>>(
        x_bf, Wt, nullptr, nullptr, N, z_bf);
    el_er_kernel<<<(N * NH + 255) / 256, 256, 0, stream>>>(
        z_bf, attn_l, attn_r, el, er, N);

    for (int l = 0; l < L; ++l) {
        float* xo = out + (size_t)l * N * DM;
        const int has_next = (l + 1 < L) ? 1 : 0;
        const short* Wnt = has_next ? (Wt + (size_t)(l + 1) * DM * DM) : Wt;

        gat_agg_ln_kernel<<<(N + 7) / 8, 256, 0, stream>>>(
            row_ptr, csr_src, z_bf, el, er, convb + (size_t)l * DM, a_conv + l,
            ln_scale + (size_t)l * DM, ln_bias + (size_t)l * DM, h_bf, hn_bf, N);

        // xo = prelu(hn@W1+b1)@W2 + b2 + h ; z_bf = bf16(xo)@W[l+1]  (one kernel)
        ffn12z<<<gM64, 512, 0, stream>>>(
            hn_bf, W1t + (size_t)l * DFF * DM, W2t + (size_t)l * DM * DFF,
            h_bf, b1 + (size_t)l * DFF, b2 + (size_t)l * DM, a_ff + l,
            Wnt, has_next, N, xo, z_bf);

        if (has_next)
            el_er_kernel<<<(N * NH + 255) / 256, 256, 0, stream>>>(
                z_bf, attn_l + (size_t)(l + 1) * NH * 16,
                attn_r + (size_t)(l + 1) * NH * 16, el, er, N);
    }
}